// Round 23
// baseline (3830.190 us; speedup 1.0000x reference)
//
#include <hip/hip_runtime.h>
#include <hip/hip_bf16.h>
#include <math.h>

// ============================================================================
// PPGPeakPerformer forward on MI355X (gfx950)  —  FINAL (r23 == r22, locked)
// B=32 S=4096 D=256 DH=128 H=8 HD=32 F=64 L=4
// Session trajectory: 6692us (first pass) -> 3803us (-43%), absmax 0.015625.
// Structure:
//  - 128xBN bf16 MFMA GEMM (BN=128 wide-N, BN=64 narrow-N): BK=32, A-panel
//    triple-buffered depth-2 prefetch with counted s_waitcnt vmcnt(2), B
//    double-buffered depth-1, raw s_barrier + sched_barrier, setprio around
//    MFMA, both-sides XOR swizzle (slot^((row>>1)&3)) via pre-swizzled
//    global source + linear global_load_lds dest, 40KB LDS -> 4 blocks/CU
//    (launch_bounds(256,4): 5+ waves/SIMD trips the VGPR allocator cliff),
//    bijective XCD chunk-remap (n-tile fastest) for A-panel L2 locality.
//  - Fused q/k RF projection: softplus((x@Wq+b)@rf) == softplus(x@(Wq@rf)
//    +(b@rf)) -> single N=1280 GEMM with block-uniform softplus epilogue.
//  - kv_partial: reg-prefetch LDS double-buffer, 1 barrier/iter, 6 blocks/CU.
//  - kv_reduce_b (once per bh, quarter-panel blocks) -> [48][72] bf16 B-panel;
//    combine_mfma vector-copies it to LDS, 6 blocks/CU.
//  - ln 16-row blocks with XCD map matching GEMM m-chunks; no memsets (pads
//    zeroed in conv1/cast_pad); tiled weight transposes; conv_final 4-lane.
//  - LN stays a separate pass: LN-GEMM fusion refuted numerically (r14/r15:
//    reduction-order change pushed absmax 0.0156 -> 0.0234 > 0.02).
// ============================================================================

typedef __bf16 bf16_t;
typedef __bf16 bf16x8 __attribute__((ext_vector_type(8)));
typedef __bf16 bf16x4 __attribute__((ext_vector_type(4)));
typedef float  f32x4  __attribute__((ext_vector_type(4)));

#define DEV __device__ __forceinline__

DEV float erf_fast(float x) {
  float ax = fabsf(x);
  float t = __builtin_amdgcn_rcpf(1.f + 0.3275911f * ax);
  float p = t * (0.254829592f + t * (-0.284496736f + t * (1.421413741f +
            t * (-1.453152027f + t * 1.061405429f))));
  float r = 1.f - p * __expf(-ax * ax);
  return copysignf(r, x);
}
DEV float geluf(float v) { return 0.5f * v * (1.f + erf_fast(v * 0.70710678118654752440f)); }
DEV float softplusf(float v) {
  float e = __expf(-fabsf(v));
  return fmaxf(v, 0.f) + __logf(1.f + e);
}

// Direct global->LDS 16B staging. LDS dest is wave-uniform base + lane*16.
DEV void gload16(const bf16_t* g, bf16_t* l) {
  __builtin_amdgcn_global_load_lds(
      (const __attribute__((address_space(1))) void*)g,
      (__attribute__((address_space(3))) void*)l, 16, 0, 0);
}

// ---------------------------------------------------------------------------
// GEMM: C[m,n] = sum_k A[m,k]*Bt[n,k].  A bf16 (batched rows), Bt bf16 [N][K].
// EPI: 1 = +bias +resid -> fp32; 2 = gelu(+bias) -> bf16;
//      3 = gelu(scale*x+bias)+pe -> fp32; 4 = gelu(scale*x+bias) -> bf16;
//      5 = tile<1024 ? softplus(+bias) : (+bias) -> bf16 (block-uniform)
// Pipeline per iter t:
//   wait vmcnt(2); s_barrier; stage B(t+1); stage A(t+2); ds_read; MFMA.
// A slack ~2 iters (HBM-ok), B slack ~1 iter (L2-ok).
// ---------------------------------------------------------------------------
template <int EPI, int K, int BN, int NTL>
__global__ __launch_bounds__(256, 4)
void gemm_bf16(const bf16_t* __restrict__ A, const bf16_t* __restrict__ Bt,
               void* Cout, const float* __restrict__ bias,
               const float* __restrict__ scale, const float* resid,
               const float* __restrict__ pe,
               int lda, long a_bstride, int rpb,
               int N, int ldc, long c_bstride, int c_roff)
{
  constexpr int MI = (BN == 128) ? 4 : 2;   // row-fragments per wave
  __shared__ bf16_t As[3][128 * 32];
  __shared__ bf16_t Bs[2][BN * 32];
  const int t = threadIdx.x;
  const int lane = t & 63;
  const int w = t >> 6;
  const int wrow = (BN == 128) ? (w >> 1) * 64 : w * 32;
  const int wcol = (BN == 128) ? (w & 1) * 64 : 0;

  // XCD-aware bijective remap (m204): bid%8 -> XCD; XCD k gets a contiguous
  // wgid chunk (n-tile fastest) so A-tile sharers co-reside on one L2.
  const int nwg = gridDim.x;
  const int q_ = nwg >> 3, r_ = nwg & 7;
  const int xcd = blockIdx.x & 7, idx_ = blockIdx.x >> 3;
  const int wgid = (xcd < r_ ? xcd * (q_ + 1) : r_ * (q_ + 1) + (xcd - r_) * q_) + idx_;
  const long m0 = (long)(wgid / NTL) * 128;
  const int n0 = (wgid % NTL) * BN;

  const int b = (int)(m0 / rpb);
  const int s_base = (int)(m0 % rpb);
  const bf16_t* Ab = A + (long)b * a_bstride + (long)s_base * lda;
  const bf16_t* Bb = Bt + (long)n0 * K;

  // staging source (pre-swizzled): lane covers row (lane>>2) of a 16-row
  // block, 16B slot ((lane&3) ^ ((row>>1)&3)).
  const int srow = lane >> 2;
  const int sslot = (lane & 3) ^ ((srow >> 1) & 3);
  const bf16_t* aS = Ab + (long)(w * 32 + srow) * lda + sslot * 8;
  const bf16_t* bS = Bb + (long)(w * 32 + srow) * K + sslot * 8;
  const int dsto = w * 1024;  // 32 rows x 32 elems per wave

#define STAGE_A(bufidx, kk)                                 \
  {                                                         \
    bf16_t* a_ = &As[bufidx][dsto];                         \
    gload16(aS + (kk), a_);                                 \
    gload16(aS + (kk) + 16 * (long)lda, a_ + 512);          \
  }
#define STAGE_B(bufidx, kk)                                 \
  if (BN == 128 || w < 2) {                                 \
    bf16_t* b_ = &Bs[bufidx][dsto];                         \
    gload16(bS + (kk), b_);                                 \
    gload16(bS + (kk) + 16 * (long)K, b_ + 512);            \
  }

  f32x4 acc[MI][4];
#pragma unroll
  for (int i = 0; i < MI; i++)
#pragma unroll
    for (int j = 0; j < 4; j++) acc[i][j] = (f32x4){0.f, 0.f, 0.f, 0.f};

  constexpr int NT = K >> 5;
  // prologue queue order: A(0), B(0), A(1) -> wait vmcnt(2) drains A0,B0.
  STAGE_A(0, 0);
  STAGE_B(0, 0);
  if (NT > 1) STAGE_A(1, 32);

#pragma unroll
  for (int tt = 0; tt < NT; ++tt) {
    if (tt + 1 < NT) {
      asm volatile("s_waitcnt vmcnt(2)" ::: "memory");
    } else {
      asm volatile("s_waitcnt vmcnt(0)" ::: "memory");
    }
    __builtin_amdgcn_s_barrier();
    __builtin_amdgcn_sched_barrier(0);
    if (tt + 1 < NT) STAGE_B((tt + 1) & 1, (tt + 1) * 32);
    if (tt + 2 < NT) STAGE_A((tt + 2) % 3, (tt + 2) * 32);
    const bf16_t* Acur = As[tt % 3];
    const bf16_t* Bcur = Bs[tt & 1];
    const int kb = (lane >> 4) * 16;
    bf16x8 af[MI], bfr[4];
#pragma unroll
    for (int i = 0; i < MI; i++) {
      int rA = wrow + i * 16 + (lane & 15);
      af[i] = *(const bf16x8*)((const char*)Acur + rA * 64 + (kb ^ (((rA >> 1) & 3) << 4)));
    }
#pragma unroll
    for (int j = 0; j < 4; j++) {
      int rB = wcol + j * 16 + (lane & 15);
      bfr[j] = *(const bf16x8*)((const char*)Bcur + rB * 64 + (kb ^ (((rB >> 1) & 3) << 4)));
    }
    __builtin_amdgcn_s_setprio(1);
#pragma unroll
    for (int mi = 0; mi < MI; mi++)
#pragma unroll
      for (int ni = 0; ni < 4; ni++)
        acc[mi][ni] = __builtin_amdgcn_mfma_f32_16x16x32_bf16(af[mi], bfr[ni], acc[mi][ni], 0, 0, 0);
    __builtin_amdgcn_s_setprio(0);
  }
#undef STAGE_A
#undef STAGE_B

  const int colbase = n0 + wcol + (lane & 15);
  float bias_r[4], scale_r[4];
#pragma unroll
  for (int ni = 0; ni < 4; ni++) {
    int col = colbase + ni * 16;
    bias_r[ni] = bias[col];
    scale_r[ni] = (EPI == 3 || EPI == 4) ? scale[col] : 0.f;
  }
  // EPI 5: softplus applies to the whole 64-col warp-tile or none of it
  // (tile boundary at col 1024 is 64-aligned) -> wave-uniform branch.
  const bool spAll = (EPI == 5) && ((n0 + wcol) < 1024);
#pragma unroll
  for (int mi = 0; mi < MI; mi++) {
#pragma unroll
    for (int j = 0; j < 4; j++) {
      int row = wrow + mi * 16 + ((lane >> 4) << 2) + j;
      long s = s_base + row;
      long cro = (long)b * c_bstride + (s + c_roff) * (long)ldc;
#pragma unroll
      for (int ni = 0; ni < 4; ni++) {
        int col = colbase + ni * 16;
        float v = acc[mi][ni][j];
        if constexpr (EPI == 1) {
          v += bias_r[ni] + resid[cro + col];
          ((float*)Cout)[cro + col] = v;
        } else if constexpr (EPI == 2) {
          v = geluf(v + bias_r[ni]);
          ((bf16_t*)Cout)[cro + col] = (bf16_t)v;
        } else if constexpr (EPI == 3) {
          v = geluf(v * scale_r[ni] + bias_r[ni]) + pe[s * 256 + col];
          ((float*)Cout)[cro + col] = v;
        } else if constexpr (EPI == 4) {
          v = geluf(v * scale_r[ni] + bias_r[ni]);
          ((bf16_t*)Cout)[cro + col] = (bf16_t)v;
        } else {  // 5
          v += bias_r[ni];
          if (spAll) v = softplusf(v);
          ((bf16_t*)Cout)[cro + col] = (bf16_t)v;
        }
      }
    }
  }
}

// ---------------------------------------------------------------------------
// LayerNorm over D=256, fp32 in -> bf16 out. 16 rows/block (4 waves x 4
// iterations), gamma/beta hoisted. XCD chunk-remap matches GEMM m-chunk map.
// ---------------------------------------------------------------------------
__global__ __launch_bounds__(256)
void ln_kernel(const float* __restrict__ h, const float* __restrict__ g,
               const float* __restrict__ bta, bf16_t* __restrict__ out)
{
  int t = threadIdx.x;
  int lane = t & 63;
  const int G = gridDim.x;                 // divisible by 8
  const int wgid = (blockIdx.x & 7) * (G >> 3) + (blockIdx.x >> 3);
  const long row0 = (long)wgid * 16 + (t >> 6);
  const int c = lane * 4;
  const float4 gv = *(const float4*)(g + c);
  const float4 bv = *(const float4*)(bta + c);
#pragma unroll
  for (int it = 0; it < 4; ++it) {
    long row = row0 + it * 4;
    const float* hp = h + row * 256 + c;
    float4 v = *(const float4*)hp;
    float s = v.x + v.y + v.z + v.w;
    float q = v.x * v.x + v.y * v.y + v.z * v.z + v.w * v.w;
#pragma unroll
    for (int m = 32; m >= 1; m >>= 1) {
      s += __shfl_xor(s, m);
      q += __shfl_xor(q, m);
    }
    float mean = s * 0.00390625f;
    float var = q * 0.00390625f - mean * mean;
    float rstd = rsqrtf(var + 1e-5f);
    bf16x4 o;
    o[0] = (bf16_t)((v.x - mean) * rstd * gv.x + bv.x);
    o[1] = (bf16_t)((v.y - mean) * rstd * gv.y + bv.y);
    o[2] = (bf16_t)((v.z - mean) * rstd * gv.z + bv.z);
    o[3] = (bf16_t)((v.w - mean) * rstd * gv.w + bv.w);
    *(bf16x4*)(out + row * 256 + c) = o;
  }
}

// ---------------------------------------------------------------------------
// Embedding conv1: x[Bc,S] -> gelu(bn(conv1d k=7 pad=3)) -> h1p[Bc,S+4,128]
// Also zeroes h1p pad rows (0,1 at s0==0; 4098,4099 at s0==4032).
// ---------------------------------------------------------------------------
__global__ __launch_bounds__(256)
void conv1_kernel(const float* __restrict__ x, const float* __restrict__ w1,
                  const float* __restrict__ sc, const float* __restrict__ sb,
                  bf16_t* __restrict__ h1p)
{
  int b = blockIdx.x >> 6;
  int s0 = (blockIdx.x & 63) << 6;
  __shared__ float xs[70];
  __shared__ float ws[896];
  int t = threadIdx.x;
  if (t < 70) {
    int s = s0 + t - 3;
    xs[t] = (s >= 0 && s < 4096) ? x[(long)b * 4096 + s] : 0.f;
  }
  for (int i = t; i < 896; i += 256) ws[i] = w1[i];
  // zero pad rows (disjoint from data rows 2..4097)
  if (s0 == 0)
    h1p[((long)b * 4100 + (t >> 7)) * 128 + (t & 127)] = (bf16_t)0.f;
  if (s0 == 4032)
    h1p[((long)b * 4100 + 4098 + (t >> 7)) * 128 + (t & 127)] = (bf16_t)0.f;
  __syncthreads();
  int c = t & 127, so = t >> 7;
  float wr[7];
#pragma unroll
  for (int k = 0; k < 7; k++) wr[k] = ws[c * 7 + k];
  float scl = sc[c], sbv = sb[c];
  for (int p = 0; p < 32; p++) {
    int sl = p * 2 + so;
    float a = 0.f;
#pragma unroll
    for (int k = 0; k < 7; k++) a += xs[sl + k] * wr[k];
    a = geluf(a * scl + sbv);
    h1p[((long)b * 4100 + s0 + sl + 2) * 128 + c] = (bf16_t)a;
  }
}

// ---------------------------------------------------------------------------
// kv partial: per (b,h,chunk of 512 s): acc[f][d] += kp[s,f]*v[s,d]; +ksum.
// Reg-prefetch double-buffer, 1 barrier/iter; accumulation order unchanged.
// ---------------------------------------------------------------------------
__global__ __launch_bounds__(256, 6)
void kv_partial(const bf16_t* __restrict__ qpkpv,
                float* __restrict__ pkv, float* __restrict__ pks)
{
  int bh = blockIdx.x >> 3, ch = blockIdx.x & 7;
  int b = bh >> 3, hh = bh & 7;
  int s0 = ch * 512;
  __shared__ float kps[2][32 * 64];
  __shared__ float vs[2][32 * 32];
  int t = threadIdx.x;
  int f = t & 63, dg = t >> 6;
  float acc[8] = {0.f, 0.f, 0.f, 0.f, 0.f, 0.f, 0.f, 0.f};
  float ks = 0.f;
  const int row = t >> 3, slot8 = (t & 7) * 8, slot4 = (t & 7) * 4;

  // prologue: tile 0 -> regs -> buf0
  bf16x8 k8;
  bf16x4 v4;
  {
    const bf16_t* rowp = qpkpv + ((long)b * 4096 + s0 + row) * 1280;
    k8 = *(const bf16x8*)(rowp + 512 + hh * 64 + slot8);
    v4 = *(const bf16x4*)(rowp + 1024 + hh * 32 + slot4);
  }
#pragma unroll
  for (int j = 0; j < 8; j++) kps[0][row * 64 + slot8 + j] = (float)k8[j];
#pragma unroll
  for (int j = 0; j < 4; j++) vs[0][row * 32 + slot4 + j] = (float)v4[j];
  __syncthreads();

  for (int it = 0; it < 16; ++it) {
    const int cur = it & 1;
    // prefetch tile it+1 into regs (no LDS dependency)
    bf16x8 nk8;
    bf16x4 nv4;
    if (it + 1 < 16) {
      const bf16_t* rowp = qpkpv + ((long)b * 4096 + s0 + (it + 1) * 32 + row) * 1280;
      nk8 = *(const bf16x8*)(rowp + 512 + hh * 64 + slot8);
      nv4 = *(const bf16x4*)(rowp + 1024 + hh * 32 + slot4);
    }
    // compute from buf[cur]
#pragma unroll 4
    for (int s = 0; s < 32; s++) {
      float kval = kps[cur][s * 64 + f];
      float4 v0 = *(const float4*)&vs[cur][s * 32 + dg * 8];
      float4 v1 = *(const float4*)&vs[cur][s * 32 + dg * 8 + 4];
      acc[0] += kval * v0.x; acc[1] += kval * v0.y;
      acc[2] += kval * v0.z; acc[3] += kval * v0.w;
      acc[4] += kval * v1.x; acc[5] += kval * v1.y;
      acc[6] += kval * v1.z; acc[7] += kval * v1.w;
      ks += kval;
    }
    // write tile it+1 into buf[cur^1]
    if (it + 1 < 16) {
#pragma unroll
      for (int j = 0; j < 8; j++) kps[cur ^ 1][row * 64 + slot8 + j] = (float)nk8[j];
#pragma unroll
      for (int j = 0; j < 4; j++) vs[cur ^ 1][row * 32 + slot4 + j] = (float)nv4[j];
      __syncthreads();
    }
  }
  long o = (long)blockIdx.x * 2048 + f * 32 + dg * 8;
#pragma unroll
  for (int j = 0; j < 8; j++) pkv[o + j] = acc[j];
  if (dg == 0) pks[blockIdx.x * 64 + f] = ks;
}

// ---------------------------------------------------------------------------
// kv_reduce_b: reduce the 8 chunk-partials into the exact [48][72] bf16
// B-panel layout combine_mfma stages. Same fp32 summation order.
// 4 blocks per bh (quarter-panel each).
// ---------------------------------------------------------------------------
__global__ __launch_bounds__(256)
void kv_reduce_b(const float* __restrict__ pkv, const float* __restrict__ pks,
                 bf16_t* __restrict__ kvb)
{
  int bh = blockIdx.x >> 2;
  int quarter = blockIdx.x & 3;
  int base = quarter * 864;                // 3456/4
  int t = threadIdx.x;
  for (int i = base + t; i < base + 864; i += 256) {
    int n = i / 72, f = i % 72;
    float s = 0.f;
    if (f < 64) {
      if (n < 32) {
#pragma unroll
        for (int ch = 0; ch < 8; ch++)
          s += pkv[((long)(bh * 8 + ch)) * 2048 + f * 32 + n];
      } else if (n == 32) {
#pragma unroll
        for (int ch = 0; ch < 8; ch++)
          s += pks[(bh * 8 + ch) * 64 + f];
      }
    }
    kvb[(long)bh * 3456 + i] = (bf16_t)s;
  }
}

// ---------------------------------------------------------------------------
// combine: ao[s, h*32+d] = (qp[s,:] @ kv[:,d]) / (qp[s,:]@ksum + 1e-8)
// B-panel precomputed by kv_reduce_b (straight vector copy to LDS).
// 6 blocks/CU (LDS 25.6KB, VGPR 40 -> safe).
// ---------------------------------------------------------------------------
__global__ __launch_bounds__(256, 6)
void combine_mfma(const bf16_t* __restrict__ qpkpv, const bf16_t* __restrict__ kvb,
                  bf16_t* __restrict__ ao)
{
  int bh = blockIdx.x >> 5;
  int s0 = (blockIdx.x & 31) << 7;
  int b = bh >> 3, hh = bh & 7;
  __shared__ bf16_t A_s[128 * 72];
  __shared__ bf16_t B_s[48 * 72];
  int t = threadIdx.x;
  for (int g = t; g < 1024; g += 256) {
    int row = g >> 3, slot = (g & 7) * 8;
    *(bf16x8*)&A_s[row * 72 + slot] =
        *(const bf16x8*)(qpkpv + ((long)b * 4096 + s0 + row) * 1280 + hh * 64 + slot);
  }
  {
    const bf16x8* kv8 = (const bf16x8*)(kvb + (long)bh * 3456);
    for (int i = t; i < 432; i += 256)
      ((bf16x8*)B_s)[i] = kv8[i];
  }
  __syncthreads();
  int lane = t & 63, w = t >> 6;
  f32x4 acc[2][3];
#pragma unroll
  for (int i = 0; i < 2; i++)
#pragma unroll
    for (int j = 0; j < 3; j++) acc[i][j] = (f32x4){0.f, 0.f, 0.f, 0.f};
#pragma unroll
  for (int kt = 0; kt < 2; kt++) {
    int ko = kt * 32 + (lane >> 4) * 8;
    bf16x8 a[2], bb[3];
#pragma unroll
    for (int i = 0; i < 2; i++)
      a[i] = *(const bf16x8*)&A_s[(w * 32 + i * 16 + (lane & 15)) * 72 + ko];
#pragma unroll
    for (int i = 0; i < 3; i++)
      bb[i] = *(const bf16x8*)&B_s[(i * 16 + (lane & 15)) * 72 + ko];
#pragma unroll
    for (int mi = 0; mi < 2; mi++)
#pragma unroll
      for (int ni = 0; ni < 3; ni++)
        acc[mi][ni] = __builtin_amdgcn_mfma_f32_16x16x32_bf16(a[mi], bb[ni], acc[mi][ni], 0, 0, 0);
  }
  long sbase = (long)b * 4096 + s0;
#pragma unroll
  for (int mi = 0; mi < 2; mi++)
#pragma unroll
    for (int j = 0; j < 4; j++) {
      int r = w * 32 + mi * 16 + ((lane >> 4) << 2) + j;
      float den = __shfl(acc[mi][2][j], (lane & 48)) + 1e-8f;
#pragma unroll
      for (int ni = 0; ni < 2; ni++) {
        int d = ni * 16 + (lane & 15);
        ao[(sbase + r) * 256 + hh * 32 + d] = (bf16_t)(acc[mi][ni][j] / den);
      }
    }
}

// ---------------------------------------------------------------------------
// h fp32 -> h_padded bf16 [Bc, S+4, 256] (rows offset +2). Also zeroes the
// hpad pad rows (0,1,4098,4099) and hdp pad rows (0,4097) per batch.
// ---------------------------------------------------------------------------
__global__ __launch_bounds__(256)
void cast_pad(const float* __restrict__ h, bf16_t* __restrict__ hp,
              bf16_t* __restrict__ hdp)
{
  long gid = (long)blockIdx.x * 256 + threadIdx.x;
  const int Bc = gridDim.x >> 9;           // grid = Bc*512
  if (gid < (long)Bc * 160) {
    int b = (int)(gid / 160);
    int r = (int)(gid % 160);
    bf16x8 z;
#pragma unroll
    for (int j = 0; j < 8; j++) z[j] = (bf16_t)0.f;
    if (r < 128) {
      int rr = r >> 5;                     // 0..3
      int row = (rr < 2) ? rr : 4096 + rr; // 0,1,4098,4099
      *(bf16x8*)(hp + ((long)b * 4100 + row) * 256 + (r & 31) * 8) = z;
    } else {
      int r2 = r - 128;                    // 0..31
      int row = (r2 >> 4) ? 4097 : 0;      // 0,4097
      *(bf16x8*)(hdp + ((long)b * 4098 + row) * 128 + (r2 & 15) * 8) = z;
    }
  }
  long i8 = gid * 8;
  long r = i8 >> 8;
  int c = (int)(i8 & 255);
  int b = (int)(r >> 12), s = (int)(r & 4095);
  float4 v0 = *(const float4*)(h + i8);
  float4 v1 = *(const float4*)(h + i8 + 4);
  bf16x8 o;
  o[0] = (bf16_t)v0.x; o[1] = (bf16_t)v0.y; o[2] = (bf16_t)v0.z; o[3] = (bf16_t)v0.w;
  o[4] = (bf16_t)v1.x; o[5] = (bf16_t)v1.y; o[6] = (bf16_t)v1.z; o[7] = (bf16_t)v1.w;
  *(bf16x8*)(hp + ((long)b * 4100 + s + 2) * 256 + c) = o;
}

// ---------------------------------------------------------------------------
// Final conv (DH->1, k=3, pad=1) + sigmoid -> out [Bc,S] fp32.
// 4 lanes per output (partial sums + shfl reduce); grid Bc*64 blocks.
// ---------------------------------------------------------------------------
__global__ __launch_bounds__(256)
void conv_final(const bf16_t* __restrict__ hdp, const float* __restrict__ w2,
                const float* __restrict__ b2, float* __restrict__ out)
{
  __shared__ float ws[384];
  int t = threadIdx.x;
  for (int i = t; i < 384; i += 256) ws[i] = w2[i];  // [c][k]
  __syncthreads();
  int part = t & 3;
  long idx = (long)blockIdx.x * 64 + (t >> 2);
  int b = (int)(idx >> 12);
  const bf16_t* base = hdp + ((long)b * 4098 + (idx & 4095)) * 128;
  float a = 0.f;
#pragma unroll
  for (int k = 0; k < 3; k++) {
#pragma unroll
    for (int cc = 0; cc < 4; cc++) {
      int c8 = part + cc * 4;
      bf16x8 v = *(const bf16x8*)(base + k * 128 + c8 * 8);
#pragma unroll
      for (int j = 0; j < 8; j++) a += (float)v[j] * ws[(c8 * 8 + j) * 3 + k];
    }
  }
  a += __shfl_xor(a, 1);
  a += __shfl_xor(a, 2);
  if (part == 0) out[idx] = 1.f / (1.f + __expf(-(a + b2[0])));
}

// ---------------------------------------------------------------------------
// Prep kernels (once per launch)
// ---------------------------------------------------------------------------
__global__ __launch_bounds__(256)
void prep_weff(const float* __restrict__ wq, const float* __restrict__ wk,
               const float* __restrict__ wv, const float* __restrict__ bq,
               const float* __restrict__ bk, const float* __restrict__ bv,
               const float* __restrict__ rf, bf16_t* __restrict__ weff,
               float* __restrict__ beff)
{
  long idx = (long)blockIdx.x * 256 + threadIdx.x;  // 4*1280*256
  int d = (int)(idx & 255);
  long r = idx >> 8;
  int n = (int)(r % 1280);
  int l = (int)(r / 1280);
  float val;
  if (n < 1024) {
    int qk = n >> 9;
    int h = (n >> 6) & 7;
    int f = n & 63;
    const float* w = qk ? wk : wq;
    const float* rfh = rf + ((long)(l * 8 + h) * 32) * 64 + f;
    const float* wrow = w + ((long)l * 256 + d) * 256 + h * 32;
    float s = 0.f;
#pragma unroll
    for (int hd = 0; hd < 32; hd++) s += wrow[hd] * rfh[hd * 64];
    val = s;
  } else {
    val = wv[((long)l * 256 + d) * 256 + (n - 1024)];
  }
  weff[idx] = (bf16_t)val;
  if (idx < 4 * 1280) {
    int nn = (int)(idx % 1280);
    int ll = (int)(idx / 1280);
    float bvv;
    if (nn < 1024) {
      int qk = nn >> 9;
      int h = (nn >> 6) & 7;
      int f = nn & 63;
      const float* bsrc = qk ? bk : bq;
      float s = 0.f;
      for (int hd = 0; hd < 32; hd++)
        s += bsrc[ll * 256 + h * 32 + hd] * rf[((long)(ll * 8 + h) * 32 + hd) * 64 + f];
      bvv = s;
    } else {
      bvv = bv[ll * 256 + (nn - 1024)];
    }
    beff[idx] = bvv;
  }
}

// 32x32 LDS-tiled transpose+cast: src fp32 [l][K][N] -> dst bf16 [l][N][K].
__global__ __launch_bounds__(256)
void prep_cast_t32(const float* __restrict__ src, bf16_t* __restrict__ dst,
                   int K, int N)
{
  __shared__ float tile[32][33];
  const int kt = K >> 5, nt = N >> 5;
  int bid = blockIdx.x;
  int l = bid / (kt * nt);
  int rem = bid % (kt * nt);
  int ntile = rem / kt;          // n-tile index
  int ktile = rem % kt;          // k-tile index
  int n0 = ntile * 32, k0 = ktile * 32;
  int t = threadIdx.x;
  int c = t & 31, rbase = t >> 5;  // 8 rows per pass
#pragma unroll
  for (int i = 0; i < 4; i++) {
    int r = rbase + i * 8;
    tile[r][c] = src[((long)l * K + k0 + r) * N + n0 + c];
  }
  __syncthreads();
#pragma unroll
  for (int i = 0; i < 4; i++) {
    int r = rbase + i * 8;
    dst[((long)l * N + n0 + r) * K + k0 + c] = (bf16_t)tile[c][r];
  }
}

__global__ __launch_bounds__(256)
void prep_conv_t(const float* __restrict__ w, bf16_t* __restrict__ dst, int C, int KW)
{
  long idx = (long)blockIdx.x * 256 + threadIdx.x;  // O*C*KW
  int ckw = C * KW;
  int kk = (int)(idx % ckw);
  int o = (int)(idx / ckw);
  int kw = kk / C, c = kk % C;
  dst[idx] = (bf16_t)w[((long)o * C + c) * KW + kw];
}

__global__ __launch_bounds__(256)
void prep_bn(const float* g1, const float* b1, const float* cb1,
             const float* g2, const float* b2, const float* cb2,
             const float* g3, const float* b3, const float* cb3,
             float* sc1, float* sb1, float* sc2, float* sb2,
             float* sc3, float* sb3)
{
  int t = threadIdx.x;
  const float r = rsqrtf(1.f + 1e-5f);
  if (t < 128) { float s = g1[t] * r; sc1[t] = s; sb1[t] = cb1[t] * s + b1[t]; }
  if (t < 256) { float s = g2[t] * r; sc2[t] = s; sb2[t] = cb2[t] * s + b2[t]; }
  if (t < 128) { float s = g3[t] * r; sc3[t] = s; sb3[t] = cb3[t] * s + b3[t]; }
}

__global__ __launch_bounds__(256)
void pe_fill(float* __restrict__ pe)
{
  long idx = (long)blockIdx.x * 256 + threadIdx.x;  // 4096*256
  int dcol = (int)(idx & 255);
  int s = (int)(idx >> 8);
  int i2 = dcol >> 1;
  float freq = expf(-9.210340371976184f * (float)(2 * i2) / 256.f);
  float a = (float)s * freq;
  pe[idx] = (dcol & 1) ? cosf(a) : sinf(a);
}

// ---------------------------------------------------------------------------
extern "C" void kernel_launch(void* const* d_in, const int* in_sizes, int n_in,
                              void* d_out, int out_size, void* d_ws, size_t ws_size,
                              hipStream_t stream)
{
  (void)in_sizes; (void)n_in; (void)out_size;
  const float* x      = (const float*)d_in[0];
  const float* emb_w1 = (const float*)d_in[1];
  const float* emb_b1 = (const float*)d_in[2];
  const float* bn1_g  = (const float*)d_in[3];
  const float* bn1_b  = (const float*)d_in[4];
  const float* emb_w2 = (const float*)d_in[5];
  const float* emb_b2 = (const float*)d_in[6];
  const float* bn2_g  = (const float*)d_in[7];
  const float* bn2_b  = (const float*)d_in[8];
  const float* wq     = (const float*)d_in[9];
  const float* bq     = (const float*)d_in[10];
  const float* wk     = (const float*)d_in[11];
  const float* bk     = (const float*)d_in[12];
  const float* wv     = (const float*)d_in[13];
  const float* bv     = (const float*)d_in[14];
  const float* wo     = (const float*)d_in[15];
  const float* bo     = (const float*)d_in[16];
  const float* rf     = (const float*)d_in[17];
  const float* ln1_g  = (const float*)d_in[18];
  const float* ln1_b  = (const float*)d_in[19];
  const float* ln2_g  = (const float*)d_in[20];
  const float* ln2_b  = (const float*)d_in[21];
  const float* ff_w1  = (const float*)d_in[22];
  const float* ff_b1  = (const float*)d_in[23];
  const float* ff_w2  = (const float*)d_in[24];
  const float* ff_b2  = (const float*)d_in[25];
  const float* dec_w1 = (const float*)d_in[26];
  const float* dec_b1 = (const float*)d_in[27];
  const float* bn3_g  = (const float*)d_in[28];
  const float* bn3_b  = (const float*)d_in[29];
  const float* dec_w2 = (const float*)d_in[30];
  const float* dec_b2 = (const float*)d_in[31];

  char* W = (char*)d_ws;

  // ---- fixed region (weights, ~12.2 MB; reserve 16 MB) ----
  bf16_t* weff = (bf16_t*)(W + 0);                     // 4*1280*256*2 = 2,621,440
  float*  beff = (float*)(W + 2621440);                // 20,480
  bf16_t* wot  = (bf16_t*)(W + 2641920);               // 524,288
  bf16_t* w1t  = (bf16_t*)(W + 3166208);               // 2,097,152
  bf16_t* w2t  = (bf16_t*)(W + 5263360);               // 2,097,152
  bf16_t* c2t  = (bf16_t*)(W + 7360512);               // 327,680
  bf16_t* d1t  = (bf16_t*)(W + 7688192);               // 327,680
  float*  pe   = (float*)(W + 8015872);                // 4,194,304
  float*  sc1  = (float*)(W + 12210176);
  float*  sb1  = (float*)(W + 12211200);
  float*  sc2  = (float*)(W + 12212224);
  float*  sb2  = (float*)(W + 12213248);
  float*  sc3  = (float*)(W + 12214272);
  float*  sb3  = (float*)(W + 12215296);
  const size_t FIXED_END = 16777216;

  // ---- pick batch chunk Bc so workspace fits ws_size ----
  // per-B: h 4MB + ao 2MB + big 10MB + pkv 512K + pks 16K + kvb 54K
  const size_t PER_B = 17440768;
  int Bc = 32;
  while (Bc > 1 && FIXED_END + (size_t)Bc * PER_B > ws_size) Bc >>= 1;

  char* P = W + FIXED_END;
  float*  h     = (float*)P;
  bf16_t* xa    = (bf16_t*)(P + (size_t)Bc * 4194304);
  bf16_t* ao    = xa;  // xa dead after fused qkv gemm; ao dead before ln2
  char*   big   = P + (size_t)Bc * (4194304 + 2097152);
  bf16_t* qpkpv = (bf16_t*)big;
  bf16_t* f1    = (bf16_t*)big;                               // after qpkpv dead
  bf16_t* h1p   = (bf16_t*)big;                               // pre-loop
  bf16_t* hpad  = (bf16_t*)big;                               // post-loop
  bf16_t* hdp   = (bf16_t*)(big + (size_t)Bc * 4100 * 256 * 2);
  float*  pkv   = (float*)(big + (size_t)Bc * 10485760);
  float*  pks   = (float*)((char*)pkv + (size_t)Bc * 524288);
  bf16_t* kvb   = (bf16_t*)((char*)pks + (size_t)Bc * 16384);

  // ---- weight prep (once) ----
  prep_weff<<<5120, 256, 0, stream>>>(wq, wk, wv, bq, bk, bv, rf, weff, beff);
  prep_cast_t32<<<256, 256, 0, stream>>>(wo, wot, 256, 256);
  prep_cast_t32<<<1024, 256, 0, stream>>>(ff_w1, w1t, 256, 1024);
  prep_cast_t32<<<1024, 256, 0, stream>>>(ff_w2, w2t, 1024, 256);
  prep_conv_t<<<640, 256, 0, stream>>>(emb_w2, c2t, 128, 5);
  prep_conv_t<<<640, 256, 0, stream>>>(dec_w1, d1t, 256, 5);
  prep_bn<<<1, 256, 0, stream>>>(bn1_g, bn1_b, emb_b1, bn2_g, bn2_b, emb_b2,
                                 bn3_g, bn3_b, dec_b1, sc1, sb1, sc2, sb2, sc3, sb3);
  pe_fill<<<4096, 256, 0, stream>>>(pe);

  for (int c0 = 0; c0 < 32; c0 += Bc) {
    const float* xc = x + (size_t)c0 * 4096;

    // ---- embedding (conv1 zeroes its own pad rows) ----
    conv1_kernel<<<Bc * 64, 256, 0, stream>>>(xc, emb_w1, sc1, sb1, h1p);
    gemm_bf16<3, 640, 64, 4><<<Bc * 128, 256, 0, stream>>>(
        h1p, c2t, h, sb2, sc2, nullptr, pe,
        128, 4100L * 128, 4096, 256, 256, 4096L * 256, 0);

    // ---- transformer layers ----
    for (int l = 0; l < 4; l++) {
      ln_kernel<<<Bc * 256, 256, 0, stream>>>(h, ln1_g + l * 256, ln1_b + l * 256, xa);
      gemm_bf16<5, 256, 128, 10><<<Bc * 320, 256, 0, stream>>>(
          xa, weff + (long)l * 327680, qpkpv, beff + l * 1280, nullptr, nullptr, nullptr,
          256, 4096L * 256, 4096, 1280, 1280, 4096L * 1280, 0);
      kv_partial<<<Bc * 64, 256, 0, stream>>>(qpkpv, pkv, pks);
      kv_reduce_b<<<Bc * 32, 256, 0, stream>>>(pkv, pks, kvb);
      combine_mfma<<<Bc * 256, 256, 0, stream>>>(qpkpv, kvb, ao);
      gemm_bf16<1, 256, 64, 4><<<Bc * 128, 256, 0, stream>>>(
          ao, wot + (long)l * 65536, h, bo + l * 256, nullptr, h, nullptr,
          256, 4096L * 256, 4096, 256, 256, 4096L * 256, 0);
      ln_kernel<<<Bc * 256, 256, 0, stream>>>(h, ln2_g + l * 256, ln2_b + l * 256, xa);
      gemm_bf16<2, 256, 128, 8><<<Bc * 256, 256, 0, stream>>>(
          xa, w1t + (long)l * 262144, f1, ff_b1 + l * 1024, nullptr, nullptr, nullptr,
          256, 4096L * 256, 4096, 1024, 1024, 4096L * 1024, 0);
      gemm_bf16<1, 1024, 64, 4><<<Bc * 128, 256, 0, stream>>>(
          f1, w2t + (long)l * 262144, h, ff_b2 + l * 256, nullptr, h, nullptr,
          1024, 4096L * 1024, 4096, 256, 256, 4096L * 256, 0);
    }

    // ---- decoder (cast_pad zeroes hpad + hdp pad rows) ----
    cast_pad<<<Bc * 512, 256, 0, stream>>>(h, hpad, hdp);
    gemm_bf16<4, 1280, 64, 2><<<Bc * 64, 256, 0, stream>>>(
        hpad, d1t, hdp, sb3, sc3, nullptr, nullptr,
        256, 4100L * 256, 4096, 128, 128, 4098L * 128, 1);
    conv_final<<<Bc * 64, 256, 0, stream>>>(hdp, dec_w2, dec_b2,
                                            (float*)d_out + (size_t)c0 * 4096);
  }
}